// Round 8
// baseline (6498.026 us; speedup 1.0000x reference)
//
#include <hip/hip_runtime.h>
#include <hip/hip_bf16.h>

// ELMo: 2-layer bidirectional masked LSTM + LN. B=32, T=256 (255 steps), E=512, U=1024.
// R8: direction-interleaved persistent scan. 64 WGs x 512 thr; each WG owns 16 ucols of
// BOTH directions (wfF+wfB = 128 VGPR). Per round: F-phase then B-phase; polls and L3
// loads of one phase hide under the other's compute. h consumed straight from L3 into
// A-fragment registers (no h LDS). Flag protocol = R6's proven relaxed-agent scheme.

#define B_  32
#define T_  256
#define TS  255
#define E_  512
#define U_  1024
#define G4  4096
#define ROWS 8160        // TS*B_
#define SROWS 8192       // padded per-dir row stride for out0/x1/Xw

typedef __attribute__((ext_vector_type(8))) short short8;
typedef __attribute__((ext_vector_type(16))) float f32x16;

static __device__ __forceinline__ unsigned short f2bf(float f) {
    union { float f; unsigned int u; } x; x.f = f;
    unsigned int u = x.u;
    unsigned int r = (u + 0x7FFFu + ((u >> 16) & 1u)) >> 16;   // RNE
    return (unsigned short)r;
}
static __device__ __forceinline__ float bf2f(unsigned short u) {
    union { unsigned int u; float f; } x; x.u = ((unsigned int)u) << 16;
    return x.f;
}
static __device__ __forceinline__ float sigm(float x) { return 1.f / (1.f + __expf(-x)); }
static __device__ __forceinline__ float tanh_(float x) { return 2.f / (1.f + __expf(-2.f * x)) - 1.f; }

static __device__ __forceinline__ void gload_lds16(const void* g, void* l) {
    __builtin_amdgcn_global_load_lds(
        (const __attribute__((address_space(1))) unsigned int*)g,
        (__attribute__((address_space(3))) unsigned int*)l, 16, 0, 0);
}

// ---------------- embedding gather -> bf16 [32][256][512] (row = b*256+t) ----------------
__global__ __launch_bounds__(256) void gather_kernel(const int* __restrict__ x,
                                                     const float* __restrict__ emb,
                                                     unsigned short* __restrict__ ebf) {
    const int bt = blockIdx.x;
    const int tok = x[bt];
    const float* src = emb + (size_t)tok * E_;
    const int c = threadIdx.x * 2;
    float2 v = *(const float2*)(src + c);
    unsigned int pk = (unsigned int)f2bf(v.x) | ((unsigned int)f2bf(v.y) << 16);
    *(unsigned int*)(ebf + (size_t)bt * E_ + c) = pk;
}

// ---------------- weight pack -> 32x32x16 B-fragment-major bf16 ----------------
// frag (tau32, kk16): lane l: col = colmap(tau32*32 + (l&31)), k = kk16*16 + (l>>5)*8 + j.
// dst[(fid*64+l)*8], fid = tau32*KK16 + kk16.
// PERM=1: vcol = wc*64 + g*16 + uu -> actual col g*1024 + wc*16 + uu.
__global__ __launch_bounds__(256) void pack_frag(const float* __restrict__ src,
                                                 unsigned short* __restrict__ dst,
                                                 int KK16, int PERM) {
    const int fid = blockIdx.x * 4 + (threadIdx.x >> 6);
    const int lane = threadIdx.x & 63;
    const int tau = fid / KK16;
    const int kk = fid - tau * KK16;
    int vcol = tau * 32 + (lane & 31);
    int col;
    if (PERM) {
        int wc = vcol >> 6, g = (vcol >> 4) & 3, uu = vcol & 15;
        col = g * 1024 + wc * 16 + uu;
    } else col = vcol;
    const int k0 = kk * 16 + ((lane >> 5) << 3);
    unsigned int pk[4];
#pragma unroll
    for (int jj = 0; jj < 4; ++jj) {
        float v0 = src[(size_t)(k0 + jj * 2) * G4 + col];
        float v1 = src[(size_t)(k0 + jj * 2 + 1) * G4 + col];
        pk[jj] = (unsigned int)f2bf(v0) | ((unsigned int)f2bf(v1) << 16);
    }
    uint4 o; o.x = pk[0]; o.y = pk[1]; o.z = pk[2]; o.w = pk[3];
    *(uint4*)(dst + ((size_t)fid * 64 + lane) * 8) = o;
}

// ---------------- Xw GEMM: C[dir][row][4096] = A[row][K] @ W + bias (bf16 out) ----------------
template <int KK16>
__global__ __launch_bounds__(256) void gemm_xw(
    const unsigned short* __restrict__ Abase, unsigned long long adstride,
    const unsigned short* __restrict__ P0, const unsigned short* __restrict__ P1,
    const float* __restrict__ bias0, const float* __restrict__ bias1,
    unsigned short* __restrict__ C)
{
    constexpr int K = KK16 * 16;
    constexpr int NT = KK16 / 4;                   // BK=64 tiles
    __shared__ unsigned short alds[2][128 * 64];   // 2 x 16KB
    const int bm = blockIdx.x, bn = blockIdx.y, dir = blockIdx.z;
    const unsigned short* A = Abase + (size_t)dir * adstride;
    const unsigned short* P = dir ? P1 : P0;
    const float* bias = dir ? bias1 : bias0;
    unsigned short* Cd = C + (size_t)dir * SROWS * G4;
    const int tid = threadIdx.x, w = tid >> 6, lane = tid & 63;
    const int l31 = lane & 31, lhi = lane >> 5;

    f32x16 acc0, acc1;
#pragma unroll
    for (int i = 0; i < 16; ++i) { acc0[i] = 0.f; acc1[i] = 0.f; }

    const int swz_in = (lane & 7) * 16;

#define STAGE(buf, kt)                                                                     \
    {                                                                                      \
        _Pragma("unroll")                                                                  \
        for (int i = 0; i < 4; ++i) {                                                      \
            const int idx = w * 4 + i;                                                     \
            const int row = idx * 8 + (lane >> 3);                                         \
            const int inrow = swz_in ^ ((row & 7) << 4);                                   \
            const unsigned short* src = A + (size_t)(bm * 128 + row) * K + (kt) * 64 + (inrow >> 1); \
            gload_lds16(src, (char*)&alds[buf][0] + idx * 1024);                           \
        }                                                                                  \
    }

    STAGE(0, 0);
    __syncthreads();
    for (int kt = 0; kt < NT; ++kt) {
        if (kt + 1 < NT) STAGE((kt + 1) & 1, kt + 1);
        const char* ab = (const char*)&alds[kt & 1][0];
        const int arow = w * 32 + l31;
#pragma unroll
        for (int kk = 0; kk < 4; ++kk) {
            const int koff = (kk * 32 + lhi * 16) ^ ((arow & 7) << 4);
            short8 af = *(const short8*)(ab + arow * 128 + koff);
            short8 bf0 = *(const short8*)(P + ((size_t)((bn * 2 + 0) * KK16 + kt * 4 + kk) * 64 + lane) * 8);
            short8 bf1 = *(const short8*)(P + ((size_t)((bn * 2 + 1) * KK16 + kt * 4 + kk) * 64 + lane) * 8);
            acc0 = __builtin_amdgcn_mfma_f32_32x32x16_bf16(af, bf0, acc0, 0, 0, 0);
            acc1 = __builtin_amdgcn_mfma_f32_32x32x16_bf16(af, bf1, acc1, 0, 0, 0);
        }
        __syncthreads();
    }
#undef STAGE
    const int col0 = bn * 64 + l31;
    const int col1 = col0 + 32;
    const float bv0 = bias[col0], bv1 = bias[col1];
#pragma unroll
    for (int reg = 0; reg < 16; ++reg) {
        const int r = (reg & 3) + 8 * (reg >> 2) + 4 * lhi;
        const size_t row = (size_t)bm * 128 + w * 32 + r;
        Cd[row * G4 + col0] = f2bf(acc0[reg] + bv0);
        Cd[row * G4 + col1] = f2bf(acc1[reg] + bv1);
    }
}

// ---------------- persistent scan: dir-interleaved, one layer ----------------
// 64 WGs x 512 thr. WG q owns ucols [q*16, q*16+16) of BOTH dirs.
// Wave w: ct = w&1 (col-tile of 32 gatecols), kq = w>>1 (K-quarter of 256).
// wfF[16]+wfB[16] = 128 VGPR. h read straight from L3 into A-frag regs (sc0 sc1).
// hcomm: [2 slot][2 dir][32 b][1024 u] bf16. flagsF/flagsB: [64] step counters.
template <int LAYER>
__global__ __launch_bounds__(512, 2) void scan_kernel(
    const unsigned short* __restrict__ puF, const unsigned short* __restrict__ puB,
    const unsigned short* __restrict__ Xw,     // [2][SROWS][4096] (L0 row=b*256+t, L1 row=s*32+b)
    const int* __restrict__ xtok,
    unsigned short* __restrict__ hcomm,
    float* __restrict__ hstate, float* __restrict__ cstate,
    unsigned short* __restrict__ out0,         // [2][SROWS][1024] bf16
    unsigned int* __restrict__ flagsF, unsigned int* __restrict__ flagsB)
{
    constexpr int PH = (LAYER == 0) ? 0 : 1;
    __shared__ float zbuf[4][32][72];          // 36.9KB (only LDS use)

    const int q = blockIdx.x;                  // 0..63
    const int tid = threadIdx.x;
    const int w = tid >> 6, lane = tid & 63;
    const int ct = w & 1, kq = w >> 1;
    const int l31 = lane & 31, lhi = lane >> 5;

    // ---- weight preload: 16 frags per dir (tau = q*2+ct, kk16 = kq*16+k) ----
    short8 wfF[16], wfB[16];
    {
        const int tau = q * 2 + ct;
#pragma unroll
        for (int k = 0; k < 16; ++k) {
            const size_t fid = (size_t)tau * 64 + kq * 16 + k;
            wfF[k] = *(const short8*)(puF + (fid * 64 + lane) * 8);
            wfB[k] = *(const short8*)(puB + (fid * 64 + lane) * 8);
        }
    }

    // ---- cell ids: thread owns (b, uu) in both dirs ----
    const int b = tid >> 4, uu = tid & 15;
    const int ucol = q * 16 + uu;
    const int cell = b * U_ + ucol;
    float cF = cstate[cell],          hFv = hstate[cell],          oF = 0.f;
    float cB = cstate[32768 + cell],  hBv = hstate[32768 + cell],  oB = 0.f;

    const int laneoff = l31 * 2048 + kq * 512 + lhi * 16;  // byte off in [32][1024]bf16 block

    for (int s = 0; s < TS; ++s) {
        // ---- poll F (wave0) ----
        if (tid < 64) {
            while (true) {
                unsigned int v = __hip_atomic_load(flagsF + tid, __ATOMIC_RELAXED, __HIP_MEMORY_SCOPE_AGENT);
                if (__all((int)v >= s)) break;
                __builtin_amdgcn_s_sleep(1);
            }
        }
        __syncthreads();                                   // (1) hF(s) published everywhere

        const int slotR = (s + PH) & 1, slotW = slotR ^ 1;
        short8 af[16];
        {
            const char* hrdF = (const char*)hcomm + (size_t)(slotR * 2 + 0) * 65536 + laneoff;
#pragma unroll
            for (int k = 0; k < 16; ++k)
                asm volatile("global_load_dwordx4 %0, %1, off sc0 sc1"
                             : "=v"(af[k]) : "v"(hrdF + k * 32));
        }
        // ---- poll B while F loads fly (wave0) ----
        if (tid < 64) {
            while (true) {
                unsigned int v = __hip_atomic_load(flagsB + tid, __ATOMIC_RELAXED, __HIP_MEMORY_SCOPE_AGENT);
                if (__all((int)v >= s)) break;
                __builtin_amdgcn_s_sleep(1);
            }
        }
        asm volatile("s_waitcnt vmcnt(0)" ::: "memory");
        __builtin_amdgcn_sched_barrier(0);

        // ---- F MFMA ----
        f32x16 acc;
#pragma unroll
        for (int i = 0; i < 16; ++i) acc[i] = 0.f;
#pragma unroll
        for (int k = 0; k < 16; ++k)
            acc = __builtin_amdgcn_mfma_f32_32x32x16_bf16(af[k], wfF[k], acc, 0, 0, 0);
#pragma unroll
        for (int reg = 0; reg < 16; ++reg)
            zbuf[kq][(reg & 3) + 8 * (reg >> 2) + 4 * lhi][ct * 32 + l31] = acc[reg];
        __syncthreads();                                   // (2) zbufF ready; pollB confirmed

        // ---- issue B loads (hidden under F cell + sync3) ----
        {
            const char* hrdB = (const char*)hcomm + (size_t)(slotR * 2 + 1) * 65536 + laneoff;
#pragma unroll
            for (int k = 0; k < 16; ++k)
                asm volatile("global_load_dwordx4 %0, %1, off sc0 sc1"
                             : "=v"(af[k]) : "v"(hrdB + k * 32));
        }
        // ---- F cell ----
        {
            const size_t xrF = (LAYER == 0) ? ((size_t)b * T_ + s) : ((size_t)s * 32 + b);
            const unsigned short* xp = Xw + xrF * G4 + ucol;
            const float xwi = bf2f(xp[0]), xwf = bf2f(xp[1024]);
            const float xwg = bf2f(xp[2048]), xwo = bf2f(xp[3072]);
            const int mF = xtok[b * T_ + s] != 0;
            float zi_ = zbuf[0][b][uu]      + zbuf[1][b][uu]      + zbuf[2][b][uu]      + zbuf[3][b][uu]      + xwi;
            float zf_ = zbuf[0][b][16 + uu] + zbuf[1][b][16 + uu] + zbuf[2][b][16 + uu] + zbuf[3][b][16 + uu] + xwf;
            float zg_ = zbuf[0][b][32 + uu] + zbuf[1][b][32 + uu] + zbuf[2][b][32 + uu] + zbuf[3][b][32 + uu] + xwg;
            float zo_ = zbuf[0][b][48 + uu] + zbuf[1][b][48 + uu] + zbuf[2][b][48 + uu] + zbuf[3][b][48 + uu] + xwo;
            float cn = sigm(zf_) * cF + sigm(zi_) * tanh_(zg_);
            float hn = sigm(zo_) * tanh_(cn);
            if (mF) { cF = cn; hFv = hn; oF = hn; }
            __hip_atomic_store(hcomm + (size_t)(slotW * 2 + 0) * 32768 + cell, f2bf(hFv),
                               __ATOMIC_RELAXED, __HIP_MEMORY_SCOPE_AGENT);
            out0[((size_t)s * 32 + b) * U_ + ucol] = f2bf(oF);
        }
        __syncthreads();                                   // (3) drains F publish + B loads
        if (tid == 0)
            __hip_atomic_store(flagsF + q, (unsigned int)(s + 1),
                               __ATOMIC_RELAXED, __HIP_MEMORY_SCOPE_AGENT);
        asm volatile("s_waitcnt vmcnt(0)" ::: "memory");   // (free: drained at sync3)
        __builtin_amdgcn_sched_barrier(0);

        // ---- B MFMA ----
#pragma unroll
        for (int i = 0; i < 16; ++i) acc[i] = 0.f;
#pragma unroll
        for (int k = 0; k < 16; ++k)
            acc = __builtin_amdgcn_mfma_f32_32x32x16_bf16(af[k], wfB[k], acc, 0, 0, 0);
#pragma unroll
        for (int reg = 0; reg < 16; ++reg)
            zbuf[kq][(reg & 3) + 8 * (reg >> 2) + 4 * lhi][ct * 32 + l31] = acc[reg];
        __syncthreads();                                   // (4)

        // ---- B cell ----
        {
            const int tB = TS - s;
            const size_t xrB = (LAYER == 0) ? ((size_t)b * T_ + tB) : ((size_t)s * 32 + b);
            const unsigned short* xp = Xw + (size_t)SROWS * G4 + xrB * G4 + ucol;
            const float xwi = bf2f(xp[0]), xwf = bf2f(xp[1024]);
            const float xwg = bf2f(xp[2048]), xwo = bf2f(xp[3072]);
            const int mB = xtok[b * T_ + tB] != 0;
            float zi_ = zbuf[0][b][uu]      + zbuf[1][b][uu]      + zbuf[2][b][uu]      + zbuf[3][b][uu]      + xwi;
            float zf_ = zbuf[0][b][16 + uu] + zbuf[1][b][16 + uu] + zbuf[2][b][16 + uu] + zbuf[3][b][16 + uu] + xwf;
            float zg_ = zbuf[0][b][32 + uu] + zbuf[1][b][32 + uu] + zbuf[2][b][32 + uu] + zbuf[3][b][32 + uu] + xwg;
            float zo_ = zbuf[0][b][48 + uu] + zbuf[1][b][48 + uu] + zbuf[2][b][48 + uu] + zbuf[3][b][48 + uu] + xwo;
            float cn = sigm(zf_) * cB + sigm(zi_) * tanh_(zg_);
            float hn = sigm(zo_) * tanh_(cn);
            if (mB) { cB = cn; hBv = hn; oB = hn; }
            __hip_atomic_store(hcomm + (size_t)(slotW * 2 + 1) * 32768 + cell, f2bf(hBv),
                               __ATOMIC_RELAXED, __HIP_MEMORY_SCOPE_AGENT);
            out0[((size_t)SROWS + (size_t)s * 32 + b) * U_ + ucol] = f2bf(oB);
        }
        __syncthreads();                                   // (5) drains B publish
        if (tid == 0)
            __hip_atomic_store(flagsB + q, (unsigned int)(s + 1),
                               __ATOMIC_RELAXED, __HIP_MEMORY_SCOPE_AGENT);
    }
    hstate[cell] = hFv;          cstate[cell] = cF;
    hstate[32768 + cell] = hBv;  cstate[32768 + cell] = cB;
}

// ---------------- layernorm (per row of 1024) ----------------
__global__ __launch_bounds__(256) void ln_kernel(const unsigned short* __restrict__ in,
                                                 const float* __restrict__ gamma,
                                                 const float* __restrict__ beta,
                                                 unsigned short* __restrict__ outbf,
                                                 float* __restrict__ outf,
                                                 int final_) {
    const int r = blockIdx.x;          // 0..8159 (= s*32+b)
    const int dir = blockIdx.y;
    const int s = r >> 5, bb = r & 31;
    const size_t rowoff = ((size_t)dir * SROWS + r) * U_;
    const int tid = threadIdx.x;
    const int c = tid * 4;

    uint2 raw = *(const uint2*)(in + rowoff + c);
    float v0 = bf2f((unsigned short)(raw.x & 0xffff));
    float v1 = bf2f((unsigned short)(raw.x >> 16));
    float v2 = bf2f((unsigned short)(raw.y & 0xffff));
    float v3 = bf2f((unsigned short)(raw.y >> 16));

    float sum = v0 + v1 + v2 + v3;
    float sq = v0 * v0 + v1 * v1 + v2 * v2 + v3 * v3;
#pragma unroll
    for (int off = 32; off > 0; off >>= 1) {
        sum += __shfl_down(sum, off);
        sq  += __shfl_down(sq, off);
    }
    __shared__ float red[8];
    __shared__ float stats[2];
    const int wv = tid >> 6;
    if ((tid & 63) == 0) { red[wv] = sum; red[4 + wv] = sq; }
    __syncthreads();
    if (tid == 0) {
        float S = red[0] + red[1] + red[2] + red[3];
        float Q = red[4] + red[5] + red[6] + red[7];
        float mu = S * (1.f / 1024.f);
        float var = Q * (1.f / 1024.f) - mu * mu;
        stats[0] = mu;
        stats[1] = rsqrtf(var + 1e-3f);
    }
    __syncthreads();
    const float mu = stats[0], inv = stats[1];
    float y0 = (v0 - mu) * inv * gamma[c]     + beta[c];
    float y1 = (v1 - mu) * inv * gamma[c + 1] + beta[c + 1];
    float y2 = (v2 - mu) * inv * gamma[c + 2] + beta[c + 2];
    float y3 = (v3 - mu) * inv * gamma[c + 3] + beta[c + 3];

    if (!final_) {
        uint2 o;
        o.x = (unsigned int)f2bf(y0) | ((unsigned int)f2bf(y1) << 16);
        o.y = (unsigned int)f2bf(y2) | ((unsigned int)f2bf(y3) << 16);
        *(uint2*)(outbf + rowoff + c) = o;
    } else {
        const size_t tIdx = dir ? (size_t)(254 - s) : (size_t)s;
        const size_t o = (size_t)dir * ROWS * U_ + ((size_t)bb * TS + tIdx) * U_ + c;
        float4 y; y.x = y0; y.y = y1; y.z = y2; y.w = y3;
        *(float4*)(outf + o) = y;
    }
}

// ---------------- host ----------------
extern "C" void kernel_launch(void* const* d_in, const int* in_sizes, int n_in,
                              void* d_out, int out_size, void* d_ws, size_t ws_size,
                              hipStream_t stream) {
    (void)in_sizes; (void)n_in; (void)out_size; (void)ws_size;
    const int*   x   = (const int*)d_in[0];
    const float* emb = (const float*)d_in[1];
    const float* fW0 = (const float*)d_in[2];
    const float* fU0 = (const float*)d_in[3];
    const float* fb0 = (const float*)d_in[4];
    const float* bW0 = (const float*)d_in[5];
    const float* bU0 = (const float*)d_in[6];
    const float* bb0 = (const float*)d_in[7];
    const float* g0  = (const float*)d_in[8];
    const float* be0 = (const float*)d_in[9];
    const float* fW1 = (const float*)d_in[10];
    const float* fU1 = (const float*)d_in[11];
    const float* fb1 = (const float*)d_in[12];
    const float* bW1 = (const float*)d_in[13];
    const float* bU1 = (const float*)d_in[14];
    const float* bb1 = (const float*)d_in[15];
    const float* g1  = (const float*)d_in[16];
    const float* be1 = (const float*)d_in[17];

    // ---- workspace layout (state first; total = 210 MiB) ----
    const size_t MB   = 1048576;
    const size_t MB8  = 8388608;
    const size_t MB4  = 4194304;
    char* ws = (char*)d_ws;
    unsigned short* hcomm = (unsigned short*)ws;              // 256 KiB  [2][2][32][1024] bf16
    float* hstate = (float*)(ws + 262144);                    // 256 KiB  [2][32][1024]
    float* cstate = (float*)(ws + 524288);                    // 256 KiB
    unsigned int* flagsL0F = (unsigned int*)(ws + 786432);    // 64
    unsigned int* flagsL0B = (unsigned int*)(ws + 786432 + 256);
    unsigned int* flagsL1F = (unsigned int*)(ws + 786432 + 512);
    unsigned int* flagsL1B = (unsigned int*)(ws + 786432 + 768);
    // S0 at 2MiB: 32 MiB — ebf|pu0f|pu0b|pw0f|pw0b; reused as x1 after scan<0>
    char* S0 = ws + 2 * MB;
    unsigned short* ebf  = (unsigned short*)(S0);
    unsigned short* pu0f = (unsigned short*)(S0 + MB8);
    unsigned short* pu0b = (unsigned short*)(S0 + 2 * MB8);
    unsigned short* pw0f = (unsigned short*)(S0 + 3 * MB8);
    unsigned short* pw0b = (unsigned short*)(S0 + 3 * MB8 + MB4);
    unsigned short* x1   = (unsigned short*)(S0);
    // S1 at 34MiB: 16 MiB — pw1 -> pu1 (packed after gemm1)
    char* S1 = ws + 34 * MB;
    unsigned short* pw1f = (unsigned short*)(S1);
    unsigned short* pw1b = (unsigned short*)(S1 + MB8);
    unsigned short* pu1f = (unsigned short*)(S1);
    unsigned short* pu1b = (unsigned short*)(S1 + MB8);
    // out0 at 50MiB: 32 MiB
    unsigned short* out0 = (unsigned short*)(ws + 50 * MB);
    // Xw at 82MiB: 128 MiB (total 210 MiB)
    unsigned short* Xw   = (unsigned short*)(ws + 82 * MB);

    hipMemsetAsync(ws, 0, 786432 + 4096, stream);   // hcomm + states + flags

    gather_kernel<<<dim3(B_ * T_), 256, 0, stream>>>(x, emb, ebf);

    pack_frag<<<dim3(128 * 64 / 4), 256, 0, stream>>>(fU0, pu0f, 64, 1);
    pack_frag<<<dim3(128 * 64 / 4), 256, 0, stream>>>(bU0, pu0b, 64, 1);
    pack_frag<<<dim3(128 * 32 / 4), 256, 0, stream>>>(fW0, pw0f, 32, 0);
    pack_frag<<<dim3(128 * 32 / 4), 256, 0, stream>>>(bW0, pw0b, 32, 0);
    pack_frag<<<dim3(128 * 64 / 4), 256, 0, stream>>>(fW1, pw1f, 64, 0);
    pack_frag<<<dim3(128 * 64 / 4), 256, 0, stream>>>(bW1, pw1b, 64, 0);

    // Xw0 = e @ W0 + b0  (rows = b*256+t)
    gemm_xw<32><<<dim3(64, 64, 2), 256, 0, stream>>>(ebf, 0ull, pw0f, pw0b, fb0, bb0, Xw);
    scan_kernel<0><<<dim3(64), 512, 0, stream>>>(pu0f, pu0b, Xw, x, hcomm, hstate, cstate,
                                                 out0, flagsL0F, flagsL0B);
    ln_kernel<<<dim3(ROWS, 2), 256, 0, stream>>>(out0, g0, be0, x1, nullptr, 0);
    // Xw1 = x1 @ W1 + b1  (rows = s*32+b)
    gemm_xw<64><<<dim3(64, 64, 2), 256, 0, stream>>>(x1, (unsigned long long)SROWS * U_, pw1f, pw1b, fb1, bb1, Xw);
    pack_frag<<<dim3(128 * 64 / 4), 256, 0, stream>>>(fU1, pu1f, 64, 1);
    pack_frag<<<dim3(128 * 64 / 4), 256, 0, stream>>>(bU1, pu1b, 64, 1);
    scan_kernel<1><<<dim3(64), 512, 0, stream>>>(pu1f, pu1b, Xw, x, hcomm, hstate, cstate,
                                                 out0, flagsL1F, flagsL1B);
    ln_kernel<<<dim3(ROWS, 2), 256, 0, stream>>>(out0, g1, be1, nullptr, (float*)d_out, 1);
}

// Round 9
// 2491.565 us; speedup vs baseline: 2.6080x; 2.6080x over previous
//
#include <hip/hip_runtime.h>
#include <hip/hip_bf16.h>

// ELMo: 2-layer bidirectional masked LSTM + LN. B=32, T=256 (255 steps), E=512, U=1024.
// R9: R6 (proven) + 3 surgical tweaks: (1) out0 store after flag publish (drop its ack
// from the critical drain), (2) full-width XOR swizzle (r&31)<<4 on h_lds -> conflict-free
// ds_read_b128, (3) sleep-free flag poll. Sync protocol identical to R6.

#define B_  32
#define T_  256
#define TS  255
#define E_  512
#define U_  1024
#define G4  4096
#define ROWS 8160        // TS*B_
#define SROWS 8192       // padded per-dir row stride for out0/x1/Xw

typedef __attribute__((ext_vector_type(8))) short short8;
typedef __attribute__((ext_vector_type(16))) float f32x16;

static __device__ __forceinline__ unsigned short f2bf(float f) {
    union { float f; unsigned int u; } x; x.f = f;
    unsigned int u = x.u;
    unsigned int r = (u + 0x7FFFu + ((u >> 16) & 1u)) >> 16;   // RNE
    return (unsigned short)r;
}
static __device__ __forceinline__ float bf2f(unsigned short u) {
    union { unsigned int u; float f; } x; x.u = ((unsigned int)u) << 16;
    return x.f;
}
static __device__ __forceinline__ float sigm(float x) { return 1.f / (1.f + __expf(-x)); }
static __device__ __forceinline__ float tanh_(float x) { return 2.f / (1.f + __expf(-2.f * x)) - 1.f; }

static __device__ __forceinline__ void gload_lds16(const void* g, void* l) {
    __builtin_amdgcn_global_load_lds(
        (const __attribute__((address_space(1))) unsigned int*)g,
        (__attribute__((address_space(3))) unsigned int*)l, 16, 0, 0);
}

// ---------------- embedding gather -> bf16 [32][256][512] (row = b*256+t) ----------------
__global__ __launch_bounds__(256) void gather_kernel(const int* __restrict__ x,
                                                     const float* __restrict__ emb,
                                                     unsigned short* __restrict__ ebf) {
    const int bt = blockIdx.x;
    const int tok = x[bt];
    const float* src = emb + (size_t)tok * E_;
    const int c = threadIdx.x * 2;
    float2 v = *(const float2*)(src + c);
    unsigned int pk = (unsigned int)f2bf(v.x) | ((unsigned int)f2bf(v.y) << 16);
    *(unsigned int*)(ebf + (size_t)bt * E_ + c) = pk;
}

// ---------------- weight pack -> 32x32x16 B-fragment-major bf16 ----------------
__global__ __launch_bounds__(256) void pack_frag(const float* __restrict__ src,
                                                 unsigned short* __restrict__ dst,
                                                 int KK16, int PERM) {
    const int fid = blockIdx.x * 4 + (threadIdx.x >> 6);
    const int lane = threadIdx.x & 63;
    const int tau = fid / KK16;
    const int kk = fid - tau * KK16;
    int vcol = tau * 32 + (lane & 31);
    int col;
    if (PERM) {
        int wc = vcol >> 6, g = (vcol >> 4) & 3, uu = vcol & 15;
        col = g * 1024 + wc * 16 + uu;
    } else col = vcol;
    const int k0 = kk * 16 + ((lane >> 5) << 3);
    unsigned int pk[4];
#pragma unroll
    for (int jj = 0; jj < 4; ++jj) {
        float v0 = src[(size_t)(k0 + jj * 2) * G4 + col];
        float v1 = src[(size_t)(k0 + jj * 2 + 1) * G4 + col];
        pk[jj] = (unsigned int)f2bf(v0) | ((unsigned int)f2bf(v1) << 16);
    }
    uint4 o; o.x = pk[0]; o.y = pk[1]; o.z = pk[2]; o.w = pk[3];
    *(uint4*)(dst + ((size_t)fid * 64 + lane) * 8) = o;
}

// ---------------- Xw GEMM: C[dir][row][4096] = A[row][K] @ W + bias (bf16 out) ----------------
template <int KK16>
__global__ __launch_bounds__(256) void gemm_xw(
    const unsigned short* __restrict__ Abase, unsigned long long adstride,
    const unsigned short* __restrict__ P0, const unsigned short* __restrict__ P1,
    const float* __restrict__ bias0, const float* __restrict__ bias1,
    unsigned short* __restrict__ C)
{
    constexpr int K = KK16 * 16;
    constexpr int NT = KK16 / 4;                   // BK=64 tiles
    __shared__ unsigned short alds[2][128 * 64];   // 2 x 16KB
    const int bm = blockIdx.x, bn = blockIdx.y, dir = blockIdx.z;
    const unsigned short* A = Abase + (size_t)dir * adstride;
    const unsigned short* P = dir ? P1 : P0;
    const float* bias = dir ? bias1 : bias0;
    unsigned short* Cd = C + (size_t)dir * SROWS * G4;
    const int tid = threadIdx.x, w = tid >> 6, lane = tid & 63;
    const int l31 = lane & 31, lhi = lane >> 5;

    f32x16 acc0, acc1;
#pragma unroll
    for (int i = 0; i < 16; ++i) { acc0[i] = 0.f; acc1[i] = 0.f; }

    const int swz_in = (lane & 7) * 16;

#define STAGE(buf, kt)                                                                     \
    {                                                                                      \
        _Pragma("unroll")                                                                  \
        for (int i = 0; i < 4; ++i) {                                                      \
            const int idx = w * 4 + i;                                                     \
            const int row = idx * 8 + (lane >> 3);                                         \
            const int inrow = swz_in ^ ((row & 7) << 4);                                   \
            const unsigned short* src = A + (size_t)(bm * 128 + row) * K + (kt) * 64 + (inrow >> 1); \
            gload_lds16(src, (char*)&alds[buf][0] + idx * 1024);                           \
        }                                                                                  \
    }

    STAGE(0, 0);
    __syncthreads();
    for (int kt = 0; kt < NT; ++kt) {
        if (kt + 1 < NT) STAGE((kt + 1) & 1, kt + 1);
        const char* ab = (const char*)&alds[kt & 1][0];
        const int arow = w * 32 + l31;
#pragma unroll
        for (int kk = 0; kk < 4; ++kk) {
            const int koff = (kk * 32 + lhi * 16) ^ ((arow & 7) << 4);
            short8 af = *(const short8*)(ab + arow * 128 + koff);
            short8 bf0 = *(const short8*)(P + ((size_t)((bn * 2 + 0) * KK16 + kt * 4 + kk) * 64 + lane) * 8);
            short8 bf1 = *(const short8*)(P + ((size_t)((bn * 2 + 1) * KK16 + kt * 4 + kk) * 64 + lane) * 8);
            acc0 = __builtin_amdgcn_mfma_f32_32x32x16_bf16(af, bf0, acc0, 0, 0, 0);
            acc1 = __builtin_amdgcn_mfma_f32_32x32x16_bf16(af, bf1, acc1, 0, 0, 0);
        }
        __syncthreads();
    }
#undef STAGE
    const int col0 = bn * 64 + l31;
    const int col1 = col0 + 32;
    const float bv0 = bias[col0], bv1 = bias[col1];
#pragma unroll
    for (int reg = 0; reg < 16; ++reg) {
        const int r = (reg & 3) + 8 * (reg >> 2) + 4 * lhi;
        const size_t row = (size_t)bm * 128 + w * 32 + r;
        Cd[row * G4 + col0] = f2bf(acc0[reg] + bv0);
        Cd[row * G4 + col1] = f2bf(acc1[reg] + bv1);
    }
}

// ---------------- persistent scan: one layer, both dirs ----------------
// 64 WGs x 512 thr: dir = wg>>5, wq = wg&31 (32 ucols / 128 gatecols).
// Wave w: ct = w&3 (col-tile of 32 gatecols), kh = w>>2 (K-half of 512).
// Weights: wf[32] = 128 VGPR/wave. h exchange via L3 (sc0/sc1), batched single-wait loads.
template <int LAYER>
__global__ __launch_bounds__(512, 2) void scan_kernel(
    const unsigned short* __restrict__ puF, const unsigned short* __restrict__ puB,
    const unsigned short* __restrict__ Xw,     // [2][SROWS][4096] (L0 row=b*256+t, L1 row=s*32+b)
    const int* __restrict__ xtok,
    unsigned short* __restrict__ hcomm,        // [2 phase][2 dir][32][1024] bf16
    float* __restrict__ hstate, float* __restrict__ cstate,
    unsigned short* __restrict__ out0,         // [2][SROWS][1024] bf16
    unsigned int* __restrict__ flags)          // [2 dir][32] step counters
{
    constexpr int PH = (LAYER == 0) ? 0 : 1;
    __shared__ unsigned short h_lds[32768];        // 64KB: [32 rows][2048B], XOR-swizzled (r&31)
    __shared__ float zbuf[8][32][33];              // 33.8KB

    const int wg = blockIdx.x, dir = wg >> 5, wq = wg & 31;
    const int tid = threadIdx.x;
    const int w = tid >> 6, lane = tid & 63;
    const int ct = w & 3, kh = w >> 2;
    const int l31 = lane & 31, lhi = lane >> 5;
    const unsigned short* pu = dir ? puB : puF;

    // ---- weight preload: 32 frags (tau = wq*4+ct, kk16 = kh*32 + kkL) ----
    short8 wf[32];
    {
        const int tau = wq * 4 + ct;
#pragma unroll
        for (int kkL = 0; kkL < 32; ++kkL)
            wf[kkL] = *(const short8*)(pu + (((size_t)tau * 64 + kh * 32 + kkL) * 64 + lane) * 8);
    }

    // ---- cell ids: thread owns (b, uu0) and (b, uu0+1) ----
    const int b = tid >> 4, up = tid & 15, uu0 = up * 2;
    const int ch = up >> 3;
    const int um = (up & 7) * 2;
    const int ucol = wq * 32 + uu0;
    const int sbase = (dir * 32 + b) * U_ + ucol;
    float c0 = cstate[sbase], c1 = cstate[sbase + 1];
    float h0 = hstate[sbase], h1 = hstate[sbase + 1];
    float o0 = 0.f, o1 = 0.f;
    const unsigned short* xwbase = Xw + (size_t)dir * SROWS * G4;

    for (int s = 0; s < TS; ++s) {
        const int tcol = dir ? (TS - s) : s;
        // -- stage h[phase] -> LDS: 8 batched sc0/sc1 dwordx4 loads, ONE vmcnt wait --
        {
            const char* hrd = (const char*)(hcomm +
                ((size_t)((s + PH) & 1) * 2 + dir) * (32 * U_));
            uint4 hv[8];
#pragma unroll
            for (int j = 0; j < 8; ++j) {
                const void* src = hrd + ((size_t)j * 512 + tid) * 16;
                asm volatile("global_load_dwordx4 %0, %1, off sc0 sc1"
                             : "=v"(hv[j]) : "v"(src));
            }
            asm volatile("s_waitcnt vmcnt(0)" ::: "memory");
            __builtin_amdgcn_sched_barrier(0);
#pragma unroll
            for (int j = 0; j < 8; ++j) {
                const int gidx = j * 512 + tid;
                const int r = gidx >> 7;
                const int off = (gidx & 127) * 16;
                *(uint4*)((char*)h_lds + r * 2048 + (off ^ ((r & 31) << 4))) = hv[j];
            }
        }
        // -- Xw + mask prefetch (plain cached loads; written pre-dispatch) --
        const size_t xr = (LAYER == 0) ? ((size_t)b * T_ + tcol) : ((size_t)s * 32 + b);
        const unsigned short* xp = xwbase + xr * G4 + ucol;
        const unsigned int xwi = *(const unsigned int*)(xp);
        const unsigned int xwf = *(const unsigned int*)(xp + 1024);
        const unsigned int xwg = *(const unsigned int*)(xp + 2048);
        const unsigned int xwo = *(const unsigned int*)(xp + 3072);
        const int m = xtok[b * T_ + tcol] != 0;
        __syncthreads();                       // h_lds ready

        // -- MFMA: h @ U (col-tile ct, K-half kh): 32 x 32x32x16 --
        f32x16 acc;
#pragma unroll
        for (int i = 0; i < 16; ++i) acc[i] = 0.f;
        {
            const char* hb = (const char*)h_lds + l31 * 2048;
            const int swz = (l31 & 31) << 4;
#pragma unroll
            for (int kkL = 0; kkL < 32; ++kkL) {
                const int koff = (((kh * 32 + kkL) * 32) + lhi * 16) ^ swz;
                short8 af = *(const short8*)(hb + koff);
                acc = __builtin_amdgcn_mfma_f32_32x32x16_bf16(af, wf[kkL], acc, 0, 0, 0);
            }
        }
        // D: col = l31, row = (reg&3)+8*(reg>>2)+4*lhi
#pragma unroll
        for (int reg = 0; reg < 16; ++reg) {
            const int zr = (reg & 3) + 8 * (reg >> 2) + 4 * lhi;
            zbuf[w][zr][l31] = acc[reg];
        }
        __syncthreads();

        // -- elementwise cell (2 cells/thread) --
        {
            float z[4][2];
#pragma unroll
            for (int g = 0; g < 4; ++g)
#pragma unroll
                for (int j = 0; j < 2; ++j) {
                    const int lv = ch * 64 + g * 16 + um + j;
                    const int ctl = lv >> 5, c32 = lv & 31;
                    z[g][j] = zbuf[ctl][b][c32] + zbuf[4 + ctl][b][c32];
                }
            z[0][0] += bf2f((unsigned short)(xwi & 0xffff)); z[0][1] += bf2f((unsigned short)(xwi >> 16));
            z[1][0] += bf2f((unsigned short)(xwf & 0xffff)); z[1][1] += bf2f((unsigned short)(xwf >> 16));
            z[2][0] += bf2f((unsigned short)(xwg & 0xffff)); z[2][1] += bf2f((unsigned short)(xwg >> 16));
            z[3][0] += bf2f((unsigned short)(xwo & 0xffff)); z[3][1] += bf2f((unsigned short)(xwo >> 16));

            float cn = sigm(z[1][0]) * c0 + sigm(z[0][0]) * tanh_(z[2][0]);
            float hn = sigm(z[3][0]) * tanh_(cn);
            if (m) { c0 = cn; h0 = hn; o0 = hn; }
            cn = sigm(z[1][1]) * c1 + sigm(z[0][1]) * tanh_(z[2][1]);
            hn = sigm(z[3][1]) * tanh_(cn);
            if (m) { c1 = cn; h1 = hn; o1 = hn; }

            // h publish: coherent write-through (2 bf16 per thread)
            unsigned short* hwr = hcomm + (size_t)((s + PH + 1) & 1) * (2 * 32 * U_);
            __hip_atomic_store((unsigned int*)(hwr + sbase),
                               (unsigned int)f2bf(h0) | ((unsigned int)f2bf(h1) << 16),
                               __ATOMIC_RELAXED, __HIP_MEMORY_SCOPE_AGENT);
        }
        __syncthreads();                       // drains h stores (acked at L3) — out0 NOT in this drain

        // -- flag publish, THEN out0 store (out0 consumed only after kernel end) --
        if (tid == 0)
            __hip_atomic_store(flags + dir * 32 + wq, (unsigned int)(s + 1),
                               __ATOMIC_RELAXED, __HIP_MEMORY_SCOPE_AGENT);
        {
            const size_t orow = (size_t)dir * SROWS + (size_t)s * 32 + b;
            *(unsigned int*)(out0 + orow * U_ + ucol) =
                (unsigned int)f2bf(o0) | ((unsigned int)f2bf(o1) << 16);
        }
        // -- coalesced sleep-free poll --
        if (tid < 32) {
            while (true) {
                unsigned int v = __hip_atomic_load(flags + dir * 32 + tid,
                                                   __ATOMIC_RELAXED, __HIP_MEMORY_SCOPE_AGENT);
                if (__all((int)v > s)) break;
            }
        }
        __syncthreads();
    }
    hstate[sbase] = h0; hstate[sbase + 1] = h1;
    cstate[sbase] = c0; cstate[sbase + 1] = c1;
}

// ---------------- layernorm (per row of 1024) ----------------
__global__ __launch_bounds__(256) void ln_kernel(const unsigned short* __restrict__ in,
                                                 const float* __restrict__ gamma,
                                                 const float* __restrict__ beta,
                                                 unsigned short* __restrict__ outbf,
                                                 float* __restrict__ outf,
                                                 int final_) {
    const int r = blockIdx.x;          // 0..8159 (= s*32+b)
    const int dir = blockIdx.y;
    const int s = r >> 5, bb = r & 31;
    const size_t rowoff = ((size_t)dir * SROWS + r) * U_;
    const int tid = threadIdx.x;
    const int c = tid * 4;

    uint2 raw = *(const uint2*)(in + rowoff + c);
    float v0 = bf2f((unsigned short)(raw.x & 0xffff));
    float v1 = bf2f((unsigned short)(raw.x >> 16));
    float v2 = bf2f((unsigned short)(raw.y & 0xffff));
    float v3 = bf2f((unsigned short)(raw.y >> 16));

    float sum = v0 + v1 + v2 + v3;
    float sq = v0 * v0 + v1 * v1 + v2 * v2 + v3 * v3;
#pragma unroll
    for (int off = 32; off > 0; off >>= 1) {
        sum += __shfl_down(sum, off);
        sq  += __shfl_down(sq, off);
    }
    __shared__ float red[8];
    __shared__ float stats[2];
    const int wv = tid >> 6;
    if ((tid & 63) == 0) { red[wv] = sum; red[4 + wv] = sq; }
    __syncthreads();
    if (tid == 0) {
        float S = red[0] + red[1] + red[2] + red[3];
        float Q = red[4] + red[5] + red[6] + red[7];
        float mu = S * (1.f / 1024.f);
        float var = Q * (1.f / 1024.f) - mu * mu;
        stats[0] = mu;
        stats[1] = rsqrtf(var + 1e-3f);
    }
    __syncthreads();
    const float mu = stats[0], inv = stats[1];
    float y0 = (v0 - mu) * inv * gamma[c]     + beta[c];
    float y1 = (v1 - mu) * inv * gamma[c + 1] + beta[c + 1];
    float y2 = (v2 - mu) * inv * gamma[c + 2] + beta[c + 2];
    float y3 = (v3 - mu) * inv * gamma[c + 3] + beta[c + 3];

    if (!final_) {
        uint2 o;
        o.x = (unsigned int)f2bf(y0) | ((unsigned int)f2bf(y1) << 16);
        o.y = (unsigned int)f2bf(y2) | ((unsigned int)f2bf(y3) << 16);
        *(uint2*)(outbf + rowoff + c) = o;
    } else {
        const size_t tIdx = dir ? (size_t)(254 - s) : (size_t)s;
        const size_t o = (size_t)dir * ROWS * U_ + ((size_t)bb * TS + tIdx) * U_ + c;
        float4 y; y.x = y0; y.y = y1; y.z = y2; y.w = y3;
        *(float4*)(outf + o) = y;
    }
}

// ---------------- host ----------------
extern "C" void kernel_launch(void* const* d_in, const int* in_sizes, int n_in,
                              void* d_out, int out_size, void* d_ws, size_t ws_size,
                              hipStream_t stream) {
    (void)in_sizes; (void)n_in; (void)out_size; (void)ws_size;
    const int*   x   = (const int*)d_in[0];
    const float* emb = (const float*)d_in[1];
    const float* fW0 = (const float*)d_in[2];
    const float* fU0 = (const float*)d_in[3];
    const float* fb0 = (const float*)d_in[4];
    const float* bW0 = (const float*)d_in[5];
    const float* bU0 = (const float*)d_in[6];
    const float* bb0 = (const float*)d_in[7];
    const float* g0  = (const float*)d_in[8];
    const float* be0 = (const float*)d_in[9];
    const float* fW1 = (const float*)d_in[10];
    const float* fU1 = (const float*)d_in[11];
    const float* fb1 = (const float*)d_in[12];
    const float* bW1 = (const float*)d_in[13];
    const float* bU1 = (const float*)d_in[14];
    const float* bb1 = (const float*)d_in[15];
    const float* g1  = (const float*)d_in[16];
    const float* be1 = (const float*)d_in[17];

    // ---- aliased workspace layout (total ~219 MB) ----
    const size_t MB8  = 8388608;
    const size_t MB4  = 4194304;
    char* ws = (char*)d_ws;
    char* S0 = ws;                                           // 32 MiB, dead after scan<0>
    unsigned short* ebf  = (unsigned short*)(S0);
    unsigned short* pu0f = (unsigned short*)(S0 + MB8);
    unsigned short* pu0b = (unsigned short*)(S0 + 2 * MB8);
    unsigned short* pw0f = (unsigned short*)(S0 + 3 * MB8);
    unsigned short* pw0b = (unsigned short*)(S0 + 3 * MB8 + MB4);
    unsigned short* x1   = (unsigned short*)(S0);            // alias (after scan<0>)
    char* S1 = ws + 4 * MB8;                                 // 16 MiB
    unsigned short* pw1f = (unsigned short*)(S1);
    unsigned short* pw1b = (unsigned short*)(S1 + MB8);
    unsigned short* pu1f = (unsigned short*)(S1);            // alias (after gemm1)
    unsigned short* pu1b = (unsigned short*)(S1 + MB8);
    unsigned short* out0 = (unsigned short*)(ws + 6 * MB8);  // 32 MiB
    unsigned short* Xw   = (unsigned short*)(ws + 10 * MB8); // 128 MiB
    char* stateblob = ws + 26 * MB8;
    unsigned short* hcomm = (unsigned short*)stateblob;            // 262144 B
    float* hstate = (float*)(stateblob + 262144);
    float* cstate = (float*)(stateblob + 524288);
    unsigned int* flags = (unsigned int*)(stateblob + 786432);     // 2 layers x 64

    hipMemsetAsync(stateblob, 0, 786432 + 1024, stream);

    gather_kernel<<<dim3(B_ * T_), 256, 0, stream>>>(x, emb, ebf);

    pack_frag<<<dim3(128 * 64 / 4), 256, 0, stream>>>(fU0, pu0f, 64, 1);
    pack_frag<<<dim3(128 * 64 / 4), 256, 0, stream>>>(bU0, pu0b, 64, 1);
    pack_frag<<<dim3(128 * 32 / 4), 256, 0, stream>>>(fW0, pw0f, 32, 0);
    pack_frag<<<dim3(128 * 32 / 4), 256, 0, stream>>>(bW0, pw0b, 32, 0);
    pack_frag<<<dim3(128 * 64 / 4), 256, 0, stream>>>(fW1, pw1f, 64, 0);
    pack_frag<<<dim3(128 * 64 / 4), 256, 0, stream>>>(bW1, pw1b, 64, 0);

    // Xw0 = e @ W0 + b0  (rows = b*256+t, 8192)
    gemm_xw<32><<<dim3(64, 64, 2), 256, 0, stream>>>(ebf, 0ull, pw0f, pw0b, fb0, bb0, Xw);
    scan_kernel<0><<<dim3(64), 512, 0, stream>>>(pu0f, pu0b, Xw, x, hcomm, hstate, cstate, out0, flags);
    ln_kernel<<<dim3(ROWS, 2), 256, 0, stream>>>(out0, g0, be0, x1, nullptr, 0);
    // Xw1 = x1 @ W1 + b1  (rows = s*32+b)
    gemm_xw<64><<<dim3(64, 64, 2), 256, 0, stream>>>(x1, (unsigned long long)SROWS * U_, pw1f, pw1b, fb1, bb1, Xw);
    pack_frag<<<dim3(128 * 64 / 4), 256, 0, stream>>>(fU1, pu1f, 64, 1);
    pack_frag<<<dim3(128 * 64 / 4), 256, 0, stream>>>(bU1, pu1b, 64, 1);
    scan_kernel<1><<<dim3(64), 512, 0, stream>>>(pu1f, pu1b, Xw, x, hcomm, hstate, cstate, out0, flags + 64);
    ln_kernel<<<dim3(ROWS, 2), 256, 0, stream>>>(out0, g1, be1, nullptr, (float*)d_out, 1);
}

// Round 11
// 2452.963 us; speedup vs baseline: 2.6491x; 1.0157x over previous
//
#include <hip/hip_runtime.h>
#include <hip/hip_bf16.h>

// ELMo: 2-layer bidirectional masked LSTM + LN. B=32, T=256 (255 steps), E=512, U=1024.
// R11: R9 (proven flag protocol) + one-step-ahead Xw/mask prefetch: the per-step Xw HBM
// load is issued after the flag publish so its ~900cy latency (and cross-WG variance)
// lands in the poll window instead of the h-stage barrier drain. Protocol unchanged.

#define B_  32
#define T_  256
#define TS  255
#define E_  512
#define U_  1024
#define G4  4096
#define ROWS 8160        // TS*B_
#define SROWS 8192       // padded per-dir row stride for out0/x1/Xw

typedef __attribute__((ext_vector_type(8))) short short8;
typedef __attribute__((ext_vector_type(16))) float f32x16;

static __device__ __forceinline__ unsigned short f2bf(float f) {
    union { float f; unsigned int u; } x; x.f = f;
    unsigned int u = x.u;
    unsigned int r = (u + 0x7FFFu + ((u >> 16) & 1u)) >> 16;   // RNE
    return (unsigned short)r;
}
static __device__ __forceinline__ float bf2f(unsigned short u) {
    union { unsigned int u; float f; } x; x.u = ((unsigned int)u) << 16;
    return x.f;
}
static __device__ __forceinline__ float sigm(float x) { return 1.f / (1.f + __expf(-x)); }
static __device__ __forceinline__ float tanh_(float x) { return 2.f / (1.f + __expf(-2.f * x)) - 1.f; }

static __device__ __forceinline__ void gload_lds16(const void* g, void* l) {
    __builtin_amdgcn_global_load_lds(
        (const __attribute__((address_space(1))) unsigned int*)g,
        (__attribute__((address_space(3))) unsigned int*)l, 16, 0, 0);
}

// ---------------- embedding gather -> bf16 [32][256][512] (row = b*256+t) ----------------
__global__ __launch_bounds__(256) void gather_kernel(const int* __restrict__ x,
                                                     const float* __restrict__ emb,
                                                     unsigned short* __restrict__ ebf) {
    const int bt = blockIdx.x;
    const int tok = x[bt];
    const float* src = emb + (size_t)tok * E_;
    const int c = threadIdx.x * 2;
    float2 v = *(const float2*)(src + c);
    unsigned int pk = (unsigned int)f2bf(v.x) | ((unsigned int)f2bf(v.y) << 16);
    *(unsigned int*)(ebf + (size_t)bt * E_ + c) = pk;
}

// ---------------- weight pack -> 32x32x16 B-fragment-major bf16 ----------------
__global__ __launch_bounds__(256) void pack_frag(const float* __restrict__ src,
                                                 unsigned short* __restrict__ dst,
                                                 int KK16, int PERM) {
    const int fid = blockIdx.x * 4 + (threadIdx.x >> 6);
    const int lane = threadIdx.x & 63;
    const int tau = fid / KK16;
    const int kk = fid - tau * KK16;
    int vcol = tau * 32 + (lane & 31);
    int col;
    if (PERM) {
        int wc = vcol >> 6, g = (vcol >> 4) & 3, uu = vcol & 15;
        col = g * 1024 + wc * 16 + uu;
    } else col = vcol;
    const int k0 = kk * 16 + ((lane >> 5) << 3);
    unsigned int pk[4];
#pragma unroll
    for (int jj = 0; jj < 4; ++jj) {
        float v0 = src[(size_t)(k0 + jj * 2) * G4 + col];
        float v1 = src[(size_t)(k0 + jj * 2 + 1) * G4 + col];
        pk[jj] = (unsigned int)f2bf(v0) | ((unsigned int)f2bf(v1) << 16);
    }
    uint4 o; o.x = pk[0]; o.y = pk[1]; o.z = pk[2]; o.w = pk[3];
    *(uint4*)(dst + ((size_t)fid * 64 + lane) * 8) = o;
}

// ---------------- Xw GEMM: C[dir][row][4096] = A[row][K] @ W + bias (bf16 out) ----------------
template <int KK16>
__global__ __launch_bounds__(256) void gemm_xw(
    const unsigned short* __restrict__ Abase, unsigned long long adstride,
    const unsigned short* __restrict__ P0, const unsigned short* __restrict__ P1,
    const float* __restrict__ bias0, const float* __restrict__ bias1,
    unsigned short* __restrict__ C)
{
    constexpr int K = KK16 * 16;
    constexpr int NT = KK16 / 4;                   // BK=64 tiles
    __shared__ unsigned short alds[2][128 * 64];   // 2 x 16KB
    const int bm = blockIdx.x, bn = blockIdx.y, dir = blockIdx.z;
    const unsigned short* A = Abase + (size_t)dir * adstride;
    const unsigned short* P = dir ? P1 : P0;
    const float* bias = dir ? bias1 : bias0;
    unsigned short* Cd = C + (size_t)dir * SROWS * G4;
    const int tid = threadIdx.x, w = tid >> 6, lane = tid & 63;
    const int l31 = lane & 31, lhi = lane >> 5;

    f32x16 acc0, acc1;
#pragma unroll
    for (int i = 0; i < 16; ++i) { acc0[i] = 0.f; acc1[i] = 0.f; }

    const int swz_in = (lane & 7) * 16;

#define STAGE(buf, kt)                                                                     \
    {                                                                                      \
        _Pragma("unroll")                                                                  \
        for (int i = 0; i < 4; ++i) {                                                      \
            const int idx = w * 4 + i;                                                     \
            const int row = idx * 8 + (lane >> 3);                                         \
            const int inrow = swz_in ^ ((row & 7) << 4);                                   \
            const unsigned short* src = A + (size_t)(bm * 128 + row) * K + (kt) * 64 + (inrow >> 1); \
            gload_lds16(src, (char*)&alds[buf][0] + idx * 1024);                           \
        }                                                                                  \
    }

    STAGE(0, 0);
    __syncthreads();
    for (int kt = 0; kt < NT; ++kt) {
        if (kt + 1 < NT) STAGE((kt + 1) & 1, kt + 1);
        const char* ab = (const char*)&alds[kt & 1][0];
        const int arow = w * 32 + l31;
#pragma unroll
        for (int kk = 0; kk < 4; ++kk) {
            const int koff = (kk * 32 + lhi * 16) ^ ((arow & 7) << 4);
            short8 af = *(const short8*)(ab + arow * 128 + koff);
            short8 bf0 = *(const short8*)(P + ((size_t)((bn * 2 + 0) * KK16 + kt * 4 + kk) * 64 + lane) * 8);
            short8 bf1 = *(const short8*)(P + ((size_t)((bn * 2 + 1) * KK16 + kt * 4 + kk) * 64 + lane) * 8);
            acc0 = __builtin_amdgcn_mfma_f32_32x32x16_bf16(af, bf0, acc0, 0, 0, 0);
            acc1 = __builtin_amdgcn_mfma_f32_32x32x16_bf16(af, bf1, acc1, 0, 0, 0);
        }
        __syncthreads();
    }
#undef STAGE
    const int col0 = bn * 64 + l31;
    const int col1 = col0 + 32;
    const float bv0 = bias[col0], bv1 = bias[col1];
#pragma unroll
    for (int reg = 0; reg < 16; ++reg) {
        const int r = (reg & 3) + 8 * (reg >> 2) + 4 * lhi;
        const size_t row = (size_t)bm * 128 + w * 32 + r;
        Cd[row * G4 + col0] = f2bf(acc0[reg] + bv0);
        Cd[row * G4 + col1] = f2bf(acc1[reg] + bv1);
    }
}

// ---------------- persistent scan: one layer, both dirs ----------------
// 64 WGs x 512 thr: dir = wg>>5, wq = wg&31 (32 ucols / 128 gatecols).
// Wave w: ct = w&3 (col-tile of 32 gatecols), kh = w>>2 (K-half of 512).
// Weights: wf[32] = 128 VGPR/wave. h exchange via L3 (sc0/sc1), batched single-wait loads.
// Xw/mask for step s+1 prefetched during step s's poll window (use-before-reload).
template <int LAYER>
__global__ __launch_bounds__(512, 2) void scan_kernel(
    const unsigned short* __restrict__ puF, const unsigned short* __restrict__ puB,
    const unsigned short* __restrict__ Xw,     // [2][SROWS][4096] (L0 row=b*256+t, L1 row=s*32+b)
    const int* __restrict__ xtok,
    unsigned short* __restrict__ hcomm,        // [2 phase][2 dir][32][1024] bf16
    float* __restrict__ hstate, float* __restrict__ cstate,
    unsigned short* __restrict__ out0,         // [2][SROWS][1024] bf16
    unsigned int* __restrict__ flags)          // [2 dir][32] step counters
{
    constexpr int PH = (LAYER == 0) ? 0 : 1;
    __shared__ unsigned short h_lds[32768];        // 64KB: [32 rows][2048B], XOR-swizzled (r&31)
    __shared__ float zbuf[8][32][33];              // 33.8KB

    const int wg = blockIdx.x, dir = wg >> 5, wq = wg & 31;
    const int tid = threadIdx.x;
    const int w = tid >> 6, lane = tid & 63;
    const int ct = w & 3, kh = w >> 2;
    const int l31 = lane & 31, lhi = lane >> 5;
    const unsigned short* pu = dir ? puB : puF;

    // ---- weight preload: 32 frags (tau = wq*4+ct, kk16 = kh*32 + kkL) ----
    short8 wf[32];
    {
        const int tau = wq * 4 + ct;
#pragma unroll
        for (int kkL = 0; kkL < 32; ++kkL)
            wf[kkL] = *(const short8*)(pu + (((size_t)tau * 64 + kh * 32 + kkL) * 64 + lane) * 8);
    }

    // ---- cell ids: thread owns (b, uu0) and (b, uu0+1) ----
    const int b = tid >> 4, up = tid & 15, uu0 = up * 2;
    const int ch = up >> 3;
    const int um = (up & 7) * 2;
    const int ucol = wq * 32 + uu0;
    const int sbase = (dir * 32 + b) * U_ + ucol;
    float c0 = cstate[sbase], c1 = cstate[sbase + 1];
    float h0 = hstate[sbase], h1 = hstate[sbase + 1];
    float o0 = 0.f, o1 = 0.f;
    const unsigned short* xwbase = Xw + (size_t)dir * SROWS * G4;

    // ---- prologue: prefetch Xw/mask for s=0 ----
    unsigned int xwi, xwf, xwg, xwo;
    int m;
    {
        const int tcol0 = dir ? TS : 0;
        const size_t xr0 = (LAYER == 0) ? ((size_t)b * T_ + tcol0) : ((size_t)0 * 32 + b);
        const unsigned short* xp = xwbase + xr0 * G4 + ucol;
        xwi = *(const unsigned int*)(xp);
        xwf = *(const unsigned int*)(xp + 1024);
        xwg = *(const unsigned int*)(xp + 2048);
        xwo = *(const unsigned int*)(xp + 3072);
        m = xtok[b * T_ + tcol0] != 0;
    }

    for (int s = 0; s < TS; ++s) {
        // -- stage h[phase] -> LDS: 8 batched sc0/sc1 dwordx4 loads, ONE vmcnt wait --
        {
            const char* hrd = (const char*)(hcomm +
                ((size_t)((s + PH) & 1) * 2 + dir) * (32 * U_));
            uint4 hv[8];
#pragma unroll
            for (int j = 0; j < 8; ++j) {
                const void* src = hrd + ((size_t)j * 512 + tid) * 16;
                asm volatile("global_load_dwordx4 %0, %1, off sc0 sc1"
                             : "=v"(hv[j]) : "v"(src));
            }
            asm volatile("s_waitcnt vmcnt(0)" ::: "memory");
            __builtin_amdgcn_sched_barrier(0);
#pragma unroll
            for (int j = 0; j < 8; ++j) {
                const int gidx = j * 512 + tid;
                const int r = gidx >> 7;
                const int off = (gidx & 127) * 16;
                *(uint4*)((char*)h_lds + r * 2048 + (off ^ ((r & 31) << 4))) = hv[j];
            }
        }
        __syncthreads();                       // h_lds ready

        // -- MFMA: h @ U (col-tile ct, K-half kh): 32 x 32x32x16 --
        f32x16 acc;
#pragma unroll
        for (int i = 0; i < 16; ++i) acc[i] = 0.f;
        {
            const char* hb = (const char*)h_lds + l31 * 2048;
            const int swz = (l31 & 31) << 4;
#pragma unroll
            for (int kkL = 0; kkL < 32; ++kkL) {
                const int koff = (((kh * 32 + kkL) * 32) + lhi * 16) ^ swz;
                short8 af = *(const short8*)(hb + koff);
                acc = __builtin_amdgcn_mfma_f32_32x32x16_bf16(af, wf[kkL], acc, 0, 0, 0);
            }
        }
        // D: col = l31, row = (reg&3)+8*(reg>>2)+4*lhi
#pragma unroll
        for (int reg = 0; reg < 16; ++reg) {
            const int zr = (reg & 3) + 8 * (reg >> 2) + 4 * lhi;
            zbuf[w][zr][l31] = acc[reg];
        }
        __syncthreads();

        // -- elementwise cell (2 cells/thread), uses prefetched xw/m --
        {
            float z[4][2];
#pragma unroll
            for (int g = 0; g < 4; ++g)
#pragma unroll
                for (int j = 0; j < 2; ++j) {
                    const int lv = ch * 64 + g * 16 + um + j;
                    const int ctl = lv >> 5, c32 = lv & 31;
                    z[g][j] = zbuf[ctl][b][c32] + zbuf[4 + ctl][b][c32];
                }
            z[0][0] += bf2f((unsigned short)(xwi & 0xffff)); z[0][1] += bf2f((unsigned short)(xwi >> 16));
            z[1][0] += bf2f((unsigned short)(xwf & 0xffff)); z[1][1] += bf2f((unsigned short)(xwf >> 16));
            z[2][0] += bf2f((unsigned short)(xwg & 0xffff)); z[2][1] += bf2f((unsigned short)(xwg >> 16));
            z[3][0] += bf2f((unsigned short)(xwo & 0xffff)); z[3][1] += bf2f((unsigned short)(xwo >> 16));

            float cn = sigm(z[1][0]) * c0 + sigm(z[0][0]) * tanh_(z[2][0]);
            float hn = sigm(z[3][0]) * tanh_(cn);
            if (m) { c0 = cn; h0 = hn; o0 = hn; }
            cn = sigm(z[1][1]) * c1 + sigm(z[0][1]) * tanh_(z[2][1]);
            hn = sigm(z[3][1]) * tanh_(cn);
            if (m) { c1 = cn; h1 = hn; o1 = hn; }

            // h publish: coherent write-through (2 bf16 per thread)
            unsigned short* hwr = hcomm + (size_t)((s + PH + 1) & 1) * (2 * 32 * U_);
            __hip_atomic_store((unsigned int*)(hwr + sbase),
                               (unsigned int)f2bf(h0) | ((unsigned int)f2bf(h1) << 16),
                               __ATOMIC_RELAXED, __HIP_MEMORY_SCOPE_AGENT);
        }
        __syncthreads();                       // drains h stores (acked at L3)

        // -- flag publish, out0 store, then NEXT-step Xw/mask prefetch (poll covers HBM) --
        if (tid == 0)
            __hip_atomic_store(flags + dir * 32 + wq, (unsigned int)(s + 1),
                               __ATOMIC_RELAXED, __HIP_MEMORY_SCOPE_AGENT);
        {
            const size_t orow = (size_t)dir * SROWS + (size_t)s * 32 + b;
            *(unsigned int*)(out0 + orow * U_ + ucol) =
                (unsigned int)f2bf(o0) | ((unsigned int)f2bf(o1) << 16);
        }
        {
            const int sn = s + 1;
            const int tcoln = dir ? (TS - sn) : sn;          // in [0,255] even at sn=TS
            const size_t xrn = (LAYER == 0) ? ((size_t)b * T_ + tcoln) : ((size_t)sn * 32 + b);
            const unsigned short* xp = xwbase + xrn * G4 + ucol;
            xwi = *(const unsigned int*)(xp);
            xwf = *(const unsigned int*)(xp + 1024);
            xwg = *(const unsigned int*)(xp + 2048);
            xwo = *(const unsigned int*)(xp + 3072);
            m = xtok[b * T_ + tcoln] != 0;
        }
        // -- coalesced poll --
        if (tid < 32) {
            while (true) {
                unsigned int v = __hip_atomic_load(flags + dir * 32 + tid,
                                                   __ATOMIC_RELAXED, __HIP_MEMORY_SCOPE_AGENT);
                if (__all((int)v > s)) break;
            }
        }
        __syncthreads();
    }
    hstate[sbase] = h0; hstate[sbase + 1] = h1;
    cstate[sbase] = c0; cstate[sbase + 1] = c1;
}

// ---------------- layernorm (per row of 1024) ----------------
__global__ __launch_bounds__(256) void ln_kernel(const unsigned short* __restrict__ in,
                                                 const float* __restrict__ gamma,
                                                 const float* __restrict__ beta,
                                                 unsigned short* __restrict__ outbf,
                                                 float* __restrict__ outf,
                                                 int final_) {
    const int r = blockIdx.x;          // 0..8159 (= s*32+b)
    const int dir = blockIdx.y;
    const int s = r >> 5, bb = r & 31;
    const size_t rowoff = ((size_t)dir * SROWS + r) * U_;
    const int tid = threadIdx.x;
    const int c = tid * 4;

    uint2 raw = *(const uint2*)(in + rowoff + c);
    float v0 = bf2f((unsigned short)(raw.x & 0xffff));
    float v1 = bf2f((unsigned short)(raw.x >> 16));
    float v2 = bf2f((unsigned short)(raw.y & 0xffff));
    float v3 = bf2f((unsigned short)(raw.y >> 16));

    float sum = v0 + v1 + v2 + v3;
    float sq = v0 * v0 + v1 * v1 + v2 * v2 + v3 * v3;
#pragma unroll
    for (int off = 32; off > 0; off >>= 1) {
        sum += __shfl_down(sum, off);
        sq  += __shfl_down(sq, off);
    }
    __shared__ float red[8];
    __shared__ float stats[2];
    const int wv = tid >> 6;
    if ((tid & 63) == 0) { red[wv] = sum; red[4 + wv] = sq; }
    __syncthreads();
    if (tid == 0) {
        float S = red[0] + red[1] + red[2] + red[3];
        float Q = red[4] + red[5] + red[6] + red[7];
        float mu = S * (1.f / 1024.f);
        float var = Q * (1.f / 1024.f) - mu * mu;
        stats[0] = mu;
        stats[1] = rsqrtf(var + 1e-3f);
    }
    __syncthreads();
    const float mu = stats[0], inv = stats[1];
    float y0 = (v0 - mu) * inv * gamma[c]     + beta[c];
    float y1 = (v1 - mu) * inv * gamma[c + 1] + beta[c + 1];
    float y2 = (v2 - mu) * inv * gamma[c + 2] + beta[c + 2];
    float y3 = (v3 - mu) * inv * gamma[c + 3] + beta[c + 3];

    if (!final_) {
        uint2 o;
        o.x = (unsigned int)f2bf(y0) | ((unsigned int)f2bf(y1) << 16);
        o.y = (unsigned int)f2bf(y2) | ((unsigned int)f2bf(y3) << 16);
        *(uint2*)(outbf + rowoff + c) = o;
    } else {
        const size_t tIdx = dir ? (size_t)(254 - s) : (size_t)s;
        const size_t o = (size_t)dir * ROWS * U_ + ((size_t)bb * TS + tIdx) * U_ + c;
        float4 y; y.x = y0; y.y = y1; y.z = y2; y.w = y3;
        *(float4*)(outf + o) = y;
    }
}

// ---------------- host ----------------
extern "C" void kernel_launch(void* const* d_in, const int* in_sizes, int n_in,
                              void* d_out, int out_size, void* d_ws, size_t ws_size,
                              hipStream_t stream) {
    (void)in_sizes; (void)n_in; (void)out_size; (void)ws_size;
    const int*   x   = (const int*)d_in[0];
    const float* emb = (const float*)d_in[1];
    const float* fW0 = (const float*)d_in[2];
    const float* fU0 = (const float*)d_in[3];
    const float* fb0 = (const float*)d_in[4];
    const float* bW0 = (const float*)d_in[5];
    const float* bU0 = (const float*)d_in[6];
    const float* bb0 = (const float*)d_in[7];
    const float* g0  = (const float*)d_in[8];
    const float* be0 = (const float*)d_in[9];
    const float* fW1 = (const float*)d_in[10];
    const float* fU1 = (const float*)d_in[11];
    const float* fb1 = (const float*)d_in[12];
    const float* bW1 = (const float*)d_in[13];
    const float* bU1 = (const float*)d_in[14];
    const float* bb1 = (const float*)d_in[15];
    const float* g1  = (const float*)d_in[16];
    const float* be1 = (const float*)d_in[17];

    // ---- aliased workspace layout (total ~219 MB) ----
    const size_t MB8  = 8388608;
    const size_t MB4  = 4194304;
    char* ws = (char*)d_ws;
    char* S0 = ws;                                           // 32 MiB, dead after scan<0>
    unsigned short* ebf  = (unsigned short*)(S0);
    unsigned short* pu0f = (unsigned short*)(S0 + MB8);
    unsigned short* pu0b = (unsigned short*)(S0 + 2 * MB8);
    unsigned short* pw0f = (unsigned short*)(S0 + 3 * MB8);
    unsigned short* pw0b = (unsigned short*)(S0 + 3 * MB8 + MB4);
    unsigned short* x1   = (unsigned short*)(S0);            // alias (after scan<0>)
    char* S1 = ws + 4 * MB8;                                 // 16 MiB
    unsigned short* pw1f = (unsigned short*)(S1);
    unsigned short* pw1b = (unsigned short*)(S1 + MB8);
    unsigned short* pu1f = (unsigned short*)(S1);            // alias (after gemm1)
    unsigned short* pu1b = (unsigned short*)(S1 + MB8);
    unsigned short* out0 = (unsigned short*)(ws + 6 * MB8);  // 32 MiB
    unsigned short* Xw   = (unsigned short*)(ws + 10 * MB8); // 128 MiB
    char* stateblob = ws + 26 * MB8;
    unsigned short* hcomm = (unsigned short*)stateblob;            // 262144 B
    float* hstate = (float*)(stateblob + 262144);
    float* cstate = (float*)(stateblob + 524288);
    unsigned int* flags = (unsigned int*)(stateblob + 786432);     // 2 layers x 64

    hipMemsetAsync(stateblob, 0, 786432 + 1024, stream);

    gather_kernel<<<dim3(B_ * T_), 256, 0, stream>>>(x, emb, ebf);

    pack_frag<<<dim3(128 * 64 / 4), 256, 0, stream>>>(fU0, pu0f, 64, 1);
    pack_frag<<<dim3(128 * 64 / 4), 256, 0, stream>>>(bU0, pu0b, 64, 1);
    pack_frag<<<dim3(128 * 32 / 4), 256, 0, stream>>>(fW0, pw0f, 32, 0);
    pack_frag<<<dim3(128 * 32 / 4), 256, 0, stream>>>(bW0, pw0b, 32, 0);
    pack_frag<<<dim3(128 * 64 / 4), 256, 0, stream>>>(fW1, pw1f, 64, 0);
    pack_frag<<<dim3(128 * 64 / 4), 256, 0, stream>>>(bW1, pw1b, 64, 0);

    // Xw0 = e @ W0 + b0  (rows = b*256+t, 8192)
    gemm_xw<32><<<dim3(64, 64, 2), 256, 0, stream>>>(ebf, 0ull, pw0f, pw0b, fb0, bb0, Xw);
    scan_kernel<0><<<dim3(64), 512, 0, stream>>>(pu0f, pu0b, Xw, x, hcomm, hstate, cstate, out0, flags);
    ln_kernel<<<dim3(ROWS, 2), 256, 0, stream>>>(out0, g0, be0, x1, nullptr, 0);
    // Xw1 = x1 @ W1 + b1  (rows = s*32+b)
    gemm_xw<64><<<dim3(64, 64, 2), 256, 0, stream>>>(x1, (unsigned long long)SROWS * U_, pw1f, pw1b, fb1, bb1, Xw);
    pack_frag<<<dim3(128 * 64 / 4), 256, 0, stream>>>(fU1, pu1f, 64, 1);
    pack_frag<<<dim3(128 * 64 / 4), 256, 0, stream>>>(bU1, pu1b, 64, 1);
    scan_kernel<1><<<dim3(64), 512, 0, stream>>>(pu1f, pu1b, Xw, x, hcomm, hstate, cstate, out0, flags + 64);
    ln_kernel<<<dim3(ROWS, 2), 256, 0, stream>>>(out0, g1, be1, nullptr, (float*)d_out, 1);
}